// Round 1
// baseline (621.743 us; speedup 1.0000x reference)
//
#include <hip/hip_runtime.h>

// MPLayer: out[i,m] = (1/K) sum_{j,l,n} edges[i,j,n] * nodes[nlist[i,j],l] * w[l,m,n]
// N=50000, K=32, F=128, E=16. Two-phase MFMA (fp16 in, fp32 acc):
//   phase 1: T[i][c], c = l*16+n  (per row: one 16x16x32 MFMA per 16-wide l-tile)
//   phase 2: out = T @ W2t^T / K, W2t[m][c] = w[l,m,n]
// Workspace layout: [0, 512KB) = W2t fp16; [512KB, 512KB+12.8MB) = nodes fp16.

typedef _Float16 half8  __attribute__((ext_vector_type(8)));
typedef _Float16 half4v __attribute__((ext_vector_type(4)));
typedef float    float4v __attribute__((ext_vector_type(4)));

#define NF 128
#define NK 32
#define NE 16
#define RPB 32   // rows per block

// ---- prep: nodes fp32 -> fp16 (RNE via hardware cvt) ----
__global__ __launch_bounds__(256) void k_prep_nodes(const float* __restrict__ src,
                                                    _Float16* __restrict__ dst, int n4) {
    int i = blockIdx.x * 256 + threadIdx.x;
    if (i < n4) {
        float4v v = ((const float4v*)src)[i];
        half4v h;
        h[0] = (_Float16)v[0]; h[1] = (_Float16)v[1];
        h[2] = (_Float16)v[2]; h[3] = (_Float16)v[3];
        ((half4v*)dst)[i] = h;
    }
}

// ---- prep: w[l][m][n] fp32 -> W2t[m][l*16+n] fp16 ----
__global__ __launch_bounds__(256) void k_prep_w(const float* __restrict__ w,
                                                _Float16* __restrict__ w2t) {
    int o = blockIdx.x * 256 + threadIdx.x;   // 128*2048 = 262144 total, exact grid
    int m = o >> 11;
    int c = o & 2047;
    int l = c >> 4;
    int n = c & 15;
    w2t[o] = (_Float16)w[(l * NF + m) * NE + n];
}

// ---- main fused kernel ----
// MFMA 16x16x32 f16 layouts (HW-verified per guide):
//   A: lane holds A[m = lane&15][k = (lane>>4)*8 + jj]
//   B: lane holds B[k = (lane>>4)*8 + jj][n = lane&15]
//   C/D: lane holds D[row = (lane>>4)*4 + reg][col = lane&15]
__global__ __launch_bounds__(256, 2) void k_mp(const _Float16* __restrict__ nodes_h,
                                               const int* __restrict__ nlist,
                                               const float* __restrict__ edges,
                                               const _Float16* __restrict__ w2t,
                                               float* __restrict__ out, int N) {
    // 32 rows x 1024 fp16 chunk of T. 64KB exactly. Power-of-2 row stride would
    // put every row on bank 0, so element positions are XOR-swizzled:
    //   pos(row, cc) = cc ^ (( ((cc>>6)&3) ^ (row&7) ) << 4)
    // (touches bits 4-6 only -> preserves the 8-element/16B blocks phase 2 reads)
    __shared__ __align__(16) _Float16 s_T[RPB * 1024];

    const int tid  = threadIdx.x;
    const int wv   = tid >> 6;
    const int quad = (tid >> 4) & 3;
    const int c16  = tid & 15;
    const int row0 = blockIdx.x * RPB;

    const float4v zf = {0.0f, 0.0f, 0.0f, 0.0f};

    // Edge B-fragments: wave owns rows wv*8 .. wv*8+7; persistent across chunks.
    // fe[r] lane holds edges[row][j = quad*8+jj][n = c16] -> wave reads contiguous 2KB/row.
    half8 fe[8];
    #pragma unroll
    for (int r = 0; r < 8; ++r) {
        int rg = row0 + wv * 8 + r;
        if (rg > N - 1) rg = N - 1;                  // clamp: loads stay in-bounds, stores guarded
        const float* ep = edges + (size_t)rg * (NK * NE) + quad * (8 * NE) + c16;
        #pragma unroll
        for (int jj = 0; jj < 8; ++jj)
            fe[r][jj] = (_Float16)ep[jj * NE];
    }

    float4v a00 = zf, a01 = zf, a10 = zf, a11 = zf;  // acc[itile][mtile]
    const char* nb = (const char*)nodes_h;

    for (int ch = 0; ch < 2; ++ch) {
        // ---- phase 1: per row, 4 l-tiles of this chunk, one MFMA each ----
        #pragma unroll
        for (int r = 0; r < 8; ++r) {
            const int il = wv * 8 + r;
            int rg = row0 + il; if (rg > N - 1) rg = N - 1;
            const int4* np = (const int4*)(nlist + (size_t)rg * NK + quad * 8);
            int4 oa = np[0], ob = np[1];             // 8 neighbor ids for k = quad*8+jj
            int o0 = oa.x << 8, o1 = oa.y << 8, o2 = oa.z << 8, o3 = oa.w << 8;
            int o4 = ob.x << 8, o5 = ob.y << 8, o6 = ob.z << 8, o7 = ob.w << 8;  // byte row offsets (256B/row)
            #pragma unroll
            for (int lt = 0; lt < 4; ++lt) {
                const int cb = ((ch << 6) + (lt << 4) + c16) << 1;  // column byte offset
                half8 a;
                a[0] = *(const _Float16*)(nb + (o0 + cb));
                a[1] = *(const _Float16*)(nb + (o1 + cb));
                a[2] = *(const _Float16*)(nb + (o2 + cb));
                a[3] = *(const _Float16*)(nb + (o3 + cb));
                a[4] = *(const _Float16*)(nb + (o4 + cb));
                a[5] = *(const _Float16*)(nb + (o5 + cb));
                a[6] = *(const _Float16*)(nb + (o6 + cb));
                a[7] = *(const _Float16*)(nb + (o7 + cb));
                float4v d = __builtin_amdgcn_mfma_f32_16x16x32_f16(a, fe[r], zf, 0, 0, 0);
                #pragma unroll
                for (int g = 0; g < 4; ++g) {
                    // T element: l_local = lt*16 + quad*4 + g, n = c16
                    int cc = (lt << 8) + (quad << 6) + (g << 4) + c16;
                    int sw = cc ^ (((((cc >> 6) & 3)) ^ (il & 7)) << 4);
                    s_T[il * 1024 + sw] = (_Float16)d[g];
                }
            }
        }
        __syncthreads();

        // ---- phase 2: out_tile += T_chunk @ W2t_chunk^T ----
        // wave handles mtiles {2wv, 2wv+1} x itiles {0,1}; W2t read once per block
        const _Float16* wrow0 = w2t + ((size_t)((wv << 1) + 0) * 16 + c16) * 2048 + (ch << 10);
        const _Float16* wrow1 = w2t + ((size_t)((wv << 1) + 1) * 16 + c16) * 2048 + (ch << 10);
        const int rsw = (c16 & 7) << 4;
        #pragma unroll 4
        for (int kt = 0; kt < 32; ++kt) {
            const int cb2 = (kt << 5) + (quad << 3);            // c_local of this fragment
            const int sw2 = cb2 ^ ((((cb2 >> 6) & 3)) << 4) ^ rsw;
            half8 t0 = *(const half8*)&s_T[c16 * 1024 + sw2];          // rows 0..15
            half8 t1 = *(const half8*)&s_T[(16 + c16) * 1024 + sw2];   // rows 16..31 (same row&7 -> same rsw)
            half8 b0 = *(const half8*)(wrow0 + cb2);
            half8 b1 = *(const half8*)(wrow1 + cb2);
            a00 = __builtin_amdgcn_mfma_f32_16x16x32_f16(t0, b0, a00, 0, 0, 0);
            a10 = __builtin_amdgcn_mfma_f32_16x16x32_f16(t1, b0, a10, 0, 0, 0);
            a01 = __builtin_amdgcn_mfma_f32_16x16x32_f16(t0, b1, a01, 0, 0, 0);
            a11 = __builtin_amdgcn_mfma_f32_16x16x32_f16(t1, b1, a11, 0, 0, 0);
        }
        __syncthreads();   // before next chunk's phase 1 overwrites s_T
    }

    // ---- epilogue: D[row = quad*4+g][col = c16], scale by 1/K ----
    const float sc = 1.0f / (float)NK;
    const int mb = (wv << 5) + c16;   // wave's first mtile column
    #pragma unroll
    for (int g = 0; g < 4; ++g) {
        int i0 = row0 + (quad << 2) + g;
        int i1 = i0 + 16;
        if (i0 < N) {
            out[(size_t)i0 * NF + mb]      = a00[g] * sc;
            out[(size_t)i0 * NF + mb + 16] = a01[g] * sc;
        }
        if (i1 < N) {
            out[(size_t)i1 * NF + mb]      = a10[g] * sc;
            out[(size_t)i1 * NF + mb + 16] = a11[g] * sc;
        }
    }
}

extern "C" void kernel_launch(void* const* d_in, const int* in_sizes, int n_in,
                              void* d_out, int out_size, void* d_ws, size_t ws_size,
                              hipStream_t stream) {
    const float* nodes = (const float*)d_in[0];
    const int*   nlist = (const int*)d_in[1];
    const float* edges = (const float*)d_in[2];
    const float* w     = (const float*)d_in[3];
    float* out = (float*)d_out;

    const int N = in_sizes[0] / NF;   // 50000

    // workspace: W2t fp16 (512KB) then nodes fp16 (N*128*2 = 12.8MB); needs ~13.4MB of ws
    _Float16* w2t     = (_Float16*)d_ws;
    _Float16* nodes_h = (_Float16*)((char*)d_ws + 524288);

    const int n4 = (N * NF) / 4;                       // 1,600,000 float4s
    k_prep_nodes<<<(n4 + 255) / 256, 256, 0, stream>>>(nodes, nodes_h, n4);
    k_prep_w<<<(NF * NF * NE) / 256, 256, 0, stream>>>(w, w2t);

    const int blocks = (N + RPB - 1) / RPB;            // 1563
    k_mp<<<blocks, 256, 0, stream>>>(nodes_h, nlist, edges, w2t, out, N);
}

// Round 2
// 336.899 us; speedup vs baseline: 1.8455x; 1.8455x over previous
//
#include <hip/hip_runtime.h>

// MPLayer: out[i,m] = (1/K) sum_{j,l,n} edges[i,j,n] * nodes[nlist[i,j],l] * w[l,m,n]
// N=50000, K=32, F=128, E=16. Two-phase MFMA (fp16 in, fp32 acc):
//   phase 1: T[i][c'] (permuted c-order), per 16-wide l-tile one 16x16x32 MFMA
//   phase 2: out = T @ W2t^T / K, with W2t columns stored in the SAME permuted order
// v2: wide dwordx4 gathers -> per-wave LDS staging -> ds_read_u16 transpose
//     (kills the v1 serialized global_load_short_d16 chains + scratch traffic),
//     4 column chunks -> 40KB LDS -> 4 blocks/CU.

typedef _Float16 half8  __attribute__((ext_vector_type(8)));
typedef _Float16 half4v __attribute__((ext_vector_type(4)));
typedef float    float4v __attribute__((ext_vector_type(4)));
typedef int      int4v  __attribute__((ext_vector_type(4)));
typedef unsigned int uint;

#define NF 128
#define NK 32
#define NE 16
#define RPB 32

__global__ __launch_bounds__(256) void k_prep_nodes(const float* __restrict__ src,
                                                    _Float16* __restrict__ dst, int n4) {
    int i = blockIdx.x * 256 + threadIdx.x;
    if (i < n4) {
        float4v v = ((const float4v*)src)[i];
        half4v h;
        h[0] = (_Float16)v[0]; h[1] = (_Float16)v[1];
        h[2] = (_Float16)v[2]; h[3] = (_Float16)v[3];
        ((half4v*)dst)[i] = h;
    }
}

// W2t permuted: storage index o = m*2048 + ch*512 + ltq*64 + n*4 + g
// corresponds to w[l, m, n] with l = ch*32 + (ltq>>2)*16 + (ltq&3)*4 + g.
// This matches phase-1's T store order (D reg g innermost), making both the
// T store (ds_write_b64) and all phase-2 k-fragments contiguous.
__global__ __launch_bounds__(256) void k_prep_w(const float* __restrict__ w,
                                                _Float16* __restrict__ w2t) {
    int o  = blockIdx.x * 256 + threadIdx.x;   // 262144 total, exact grid
    int m  = o >> 11;
    int cf = o & 2047;
    int ch = cf >> 9;
    int cp = cf & 511;
    int ltq = cp >> 6;
    int n   = (cp >> 2) & 15;
    int g   = cp & 3;
    int l = ch * 32 + (ltq >> 2) * 16 + (ltq & 3) * 4 + g;
    w2t[o] = (_Float16)w[(l * NF + m) * NE + n];
}

// MFMA 16x16x32 f16 layouts (verified by v1 passing):
//   A: lane holds A[m = lane&15][k = (lane>>4)*8 + jj]
//   B: lane holds B[k = (lane>>4)*8 + jj][n = lane&15]
//   C/D: lane holds D[row = (lane>>4)*4 + g][col = lane&15]
__global__ __launch_bounds__(256, 4) void k_mp(const _Float16* __restrict__ nodes_h,
                                               const int* __restrict__ nlist,
                                               const float* __restrict__ edges,
                                               const _Float16* __restrict__ w2t,
                                               float* __restrict__ out, int N) {
    // s_T: 32 i-rows x 512 permuted-c halves per chunk, XOR-swizzled (32KB).
    // s_G: per-wave gather staging, 32 j-rows x 32 cols, block-XOR by j>>3 (8KB).
    __shared__ __align__(16) _Float16 s_T[RPB * 512];
    __shared__ __align__(16) _Float16 s_G[4 * NK * 32];

    const int tid  = threadIdx.x;
    const int wv   = tid >> 6;
    const int ln   = tid & 63;
    const int quad = ln >> 4;
    const int c16  = ln & 15;
    const int row0 = blockIdx.x * RPB;

    _Float16* __restrict__ gbuf = &s_G[wv * (NK * 32)];
    const float4v zf = {0.f, 0.f, 0.f, 0.f};

    // ---- edge B-fragments (persistent across chunks) ----
    half8 fe[8];
    #pragma unroll
    for (int r = 0; r < 8; ++r) {
        int rg = row0 + wv * 8 + r; if (rg > N - 1) rg = N - 1;
        const float* ep = edges + (size_t)rg * (NK * NE) + quad * (8 * NE) + c16;
        #pragma unroll
        for (int jj = 0; jj < 8; ++jj) fe[r][jj] = (_Float16)ep[jj * NE];
    }

    // ---- neighbor row byte-offsets: lane stages rows j=jlane and jlane+16 ----
    const int jlane = ln >> 2;       // 0..15
    const int sub   = ln & 3;        // which 16B piece of the 64B chunk-row
    int nb0[8], nb1[8];
    #pragma unroll
    for (int r = 0; r < 8; ++r) {
        int rg = row0 + wv * 8 + r; if (rg > N - 1) rg = N - 1;
        nb0[r] = nlist[rg * NK + jlane]      << 8;   // *256 bytes per fp16 node row
        nb1[r] = nlist[rg * NK + 16 + jlane] << 8;
    }
    // staging write blocks, XOR by (j>>3)&3 (matches read side where j>>3 == quad)
    const int wblk0 = (sub ^ ((jlane >> 3) & 3)) << 3;
    const int wblk1 = (sub ^ (((jlane + 16) >> 3) & 3)) << 3;

    float4v a00 = zf, a01 = zf, a10 = zf, a11 = zf;
    const char* nbase = (const char*)nodes_h;

    for (int ch = 0; ch < 4; ++ch) {
        // ================= phase 1 =================
        #pragma unroll
        for (int r = 0; r < 8; ++r) {
            const int il = wv * 8 + r;
            // gather this i-row's 32 neighbor rows, cols [ch*32, ch*32+32): two
            // independent 16B loads per lane -> one vmcnt wait, full MLP
            half8 g0 = *(const half8*)(nbase + nb0[r] + ch * 64 + sub * 16);
            half8 g1 = *(const half8*)(nbase + nb1[r] + ch * 64 + sub * 16);
            *(half8*)&gbuf[jlane * 32 + wblk0]        = g0;
            *(half8*)&gbuf[(jlane + 16) * 32 + wblk1] = g1;
            // per-wave buffer: LDS ops from one wave complete in order; no barrier
            #pragma unroll
            for (int lt = 0; lt < 2; ++lt) {
                const int col   = lt * 16 + c16;
                const int rbase = quad * (8 * 32) + (col ^ (quad << 3));
                uint t0 = *(const unsigned short*)&gbuf[rbase + 0 * 32];
                uint t1 = *(const unsigned short*)&gbuf[rbase + 1 * 32];
                uint t2 = *(const unsigned short*)&gbuf[rbase + 2 * 32];
                uint t3 = *(const unsigned short*)&gbuf[rbase + 3 * 32];
                uint t4 = *(const unsigned short*)&gbuf[rbase + 4 * 32];
                uint t5 = *(const unsigned short*)&gbuf[rbase + 5 * 32];
                uint t6 = *(const unsigned short*)&gbuf[rbase + 6 * 32];
                uint t7 = *(const unsigned short*)&gbuf[rbase + 7 * 32];
                int4v pv;
                pv[0] = (int)(t0 | (t1 << 16));
                pv[1] = (int)(t2 | (t3 << 16));
                pv[2] = (int)(t4 | (t5 << 16));
                pv[3] = (int)(t6 | (t7 << 16));
                half8 av = __builtin_bit_cast(half8, pv);
                float4v d = __builtin_amdgcn_mfma_f32_16x16x32_f16(av, fe[r], zf, 0, 0, 0);
                // T store, permuted: c' = ltq*64 + c16*4 + g  (g contiguous -> b64)
                const int ltq  = lt * 4 + quad;
                const int cb   = ltq * 64 + c16 * 4;
                const int phys = cb ^ ((((ltq ^ il) & 7)) << 3);
                half4v hv;
                hv[0] = (_Float16)d[0]; hv[1] = (_Float16)d[1];
                hv[2] = (_Float16)d[2]; hv[3] = (_Float16)d[3];
                *(half4v*)&s_T[il * 512 + phys] = hv;
            }
        }
        __syncthreads();

        // ================= phase 2 =================
        const _Float16* wr0 = w2t + ((size_t)(wv * 2 + 0) * 16 + c16) * 2048 + ch * 512;
        const _Float16* wr1 = w2t + ((size_t)(wv * 2 + 1) * 16 + c16) * 2048 + ch * 512;
        #pragma unroll 4
        for (int kt = 0; kt < 16; ++kt) {
            const int cb2  = kt * 32 + quad * 8;
            const int mask = (((cb2 >> 6) ^ c16) & 7) << 3;
            half8 t0 = *(const half8*)&s_T[c16 * 512        + (cb2 ^ mask)];
            half8 t1 = *(const half8*)&s_T[(16 + c16) * 512 + (cb2 ^ mask)];
            half8 b0 = *(const half8*)(wr0 + cb2);
            half8 b1 = *(const half8*)(wr1 + cb2);
            a00 = __builtin_amdgcn_mfma_f32_16x16x32_f16(t0, b0, a00, 0, 0, 0);
            a10 = __builtin_amdgcn_mfma_f32_16x16x32_f16(t1, b0, a10, 0, 0, 0);
            a01 = __builtin_amdgcn_mfma_f32_16x16x32_f16(t0, b1, a01, 0, 0, 0);
            a11 = __builtin_amdgcn_mfma_f32_16x16x32_f16(t1, b1, a11, 0, 0, 0);
        }
        __syncthreads();   // before next chunk's phase 1 overwrites s_T
    }

    // ---- epilogue ----
    const float sc = 1.0f / (float)NK;
    const int mb = (wv << 5) + c16;
    #pragma unroll
    for (int g = 0; g < 4; ++g) {
        int i0 = row0 + quad * 4 + g;
        int i1 = i0 + 16;
        if (i0 < N) {
            out[(size_t)i0 * NF + mb]      = a00[g] * sc;
            out[(size_t)i0 * NF + mb + 16] = a01[g] * sc;
        }
        if (i1 < N) {
            out[(size_t)i1 * NF + mb]      = a10[g] * sc;
            out[(size_t)i1 * NF + mb + 16] = a11[g] * sc;
        }
    }
}

extern "C" void kernel_launch(void* const* d_in, const int* in_sizes, int n_in,
                              void* d_out, int out_size, void* d_ws, size_t ws_size,
                              hipStream_t stream) {
    const float* nodes = (const float*)d_in[0];
    const int*   nlist = (const int*)d_in[1];
    const float* edges = (const float*)d_in[2];
    const float* w     = (const float*)d_in[3];
    float* out = (float*)d_out;

    const int N = in_sizes[0] / NF;   // 50000

    _Float16* w2t     = (_Float16*)d_ws;                       // 512KB
    _Float16* nodes_h = (_Float16*)((char*)d_ws + 524288);     // 12.8MB

    const int n4 = (N * NF) / 4;
    k_prep_nodes<<<(n4 + 255) / 256, 256, 0, stream>>>(nodes, nodes_h, n4);
    k_prep_w<<<(NF * NF * NE) / 256, 256, 0, stream>>>(w, w2t);

    const int blocks = (N + RPB - 1) / RPB;                    // 1563
    k_mp<<<blocks, 256, 0, stream>>>(nodes_h, nlist, edges, w2t, out, N);
}